// Round 9
// baseline (308.357 us; speedup 1.0000x reference)
//
#include <hip/hip_runtime.h>
#include <stdint.h>

#define T_TOK 4096
#define DM    512
#define DFF   2048
#define NE    16
#define NSLOT (T_TOK * 2)
#define NW    (NE * DFF * DM)   // 16,777,216 elems per weight tensor
#define MAXTILE 80              // max Σ ceil(cnt_e/128) = 79
#define CONVB (2 * NW / 8 / 256) // 16384 convert blocks
#define ROUTB (T_TOK / 4)        // 1024 router blocks (dispatched FIRST)
#define KSPLIT 4                 // gemm2 K-split (DFF/KSPLIT = 512 per part)

typedef __attribute__((ext_vector_type(8))) short  bf16x8;
typedef __attribute__((ext_vector_type(4))) float  f32x4;
typedef __attribute__((ext_vector_type(8))) unsigned short us8;

static __device__ __forceinline__ unsigned short f2bf(float f) {
    unsigned int u = __float_as_uint(f);
    u += 0x7FFFu + ((u >> 16) & 1u);   // RNE
    return (unsigned short)(u >> 16);
}

static __device__ __forceinline__ void gload_lds16(const void* g, void* l) {
    __builtin_amdgcn_global_load_lds(
        (const __attribute__((address_space(1))) void*)g,
        (__attribute__((address_space(3))) void*)l, 16, 0, 0);
}

// XCD-chunked logical id (verified r8: gemm2 FETCH 106->42 MB).
static __device__ __forceinline__ int xcd_chunk_logical(int bid, int total) {
    int k = bid & 7, seq = bid >> 3;
    int q = total >> 3, r = total & 7;
    int base = k * q + (k < r ? k : r);
    int len  = q + (k < r ? 1 : 0);
    return (seq < len) ? (base + seq) : total;
}

// ---- fused prologue: [0,ROUTB) router ; [ROUTB,+CONVB) w1/w2 fp32->bf16 ----
__global__ __launch_bounds__(256) void convert_router_kernel(
    const float* __restrict__ w1, const float* __restrict__ w2,
    unsigned short* __restrict__ w1b, unsigned short* __restrict__ w2b,
    const float* __restrict__ x, const float* __restrict__ rw,
    const float* __restrict__ rb, int* __restrict__ tok_e,
    float* __restrict__ tok_g, unsigned short* __restrict__ xb,
    const float* __restrict__ b2, float* __restrict__ out)
{
    __shared__ float rws[NE * DM];
    int tid = threadIdx.x;

    if (blockIdx.x >= ROUTB) {
        // -------- convert branch ----
        size_t i = ((size_t)(blockIdx.x - ROUTB) * 256 + tid) * 8;
        const float* src; unsigned short* dst;
        if (i < (size_t)NW) { src = w1 + i;        dst = w1b + i; }
        else                { src = w2 + (i - NW); dst = w2b + (i - NW); }
        f32x4 a = __builtin_nontemporal_load((const f32x4*)src);
        f32x4 b = __builtin_nontemporal_load((const f32x4*)(src + 4));
        us8 v;
        v[0] = f2bf(a.x); v[1] = f2bf(a.y); v[2] = f2bf(a.z); v[3] = f2bf(a.w);
        v[4] = f2bf(b.x); v[5] = f2bf(b.y); v[6] = f2bf(b.z); v[7] = f2bf(b.w);
        *(us8*)dst = v;
        return;
    }

    // -------- router branch ----
    for (int i = 0; i < 8; ++i) {
        int idx = (tid + i * 256) * 4;
        *(f32x4*)&rws[idx] = *(const f32x4*)&rw[idx];
    }
    __syncthreads();

    int wid = tid >> 6, lane = tid & 63;
    int t = blockIdx.x * 4 + wid;

    float xv[8];
    const float* xp = x + (size_t)t * DM + lane * 8;
    *(f32x4*)&xv[0] = *(const f32x4*)xp;
    *(f32x4*)&xv[4] = *(const f32x4*)(xp + 4);

    us8 v;
    for (int i = 0; i < 8; ++i) v[i] = f2bf(xv[i]);
    *(us8*)&xb[(size_t)t * DM + lane * 8] = v;

    float acc[NE];
    for (int e = 0; e < NE; ++e) {
        const float* wp = &rws[e * DM + lane * 8];
        float a = 0.f;
        for (int i = 0; i < 8; ++i) a += xv[i] * wp[i];
        acc[e] = a;
    }
    for (int e = 0; e < NE; ++e) {
        float v2 = acc[e];
        for (int off = 32; off > 0; off >>= 1) v2 += __shfl_xor(v2, off);
        acc[e] = v2 + rb[e];
    }
    float m = acc[0];
    for (int e = 1; e < NE; ++e) m = fmaxf(m, acc[e]);
    float p[NE]; float s = 0.f;
    for (int e = 0; e < NE; ++e) { p[e] = expf(acc[e] - m); s += p[e]; }
    float inv = 1.f / s;
    int i0 = 0; float p0 = p[0];
    for (int e = 1; e < NE; ++e) if (p[e] > p0) { p0 = p[e]; i0 = e; }
    int i1 = (i0 == 0) ? 1 : 0; float p1 = p[i1];
    for (int e = 0; e < NE; ++e)
        if (e != i0 && p[e] > p1) { p1 = p[e]; i1 = e; }
    float g0 = p0 * inv, g1 = p1 * inv;
    if (lane == 0) {
        tok_e[t * 2]     = i0;  tok_e[t * 2 + 1] = i1;
        tok_g[t * 2]     = g0;
        tok_g[t * 2 + 1] = g1;
    }
    // out init: gated biases (gemm2 atomics accumulate the matmul on top)
    {
        int d = lane * 8;
        f32x4 c0a = *(const f32x4*)&b2[i0 * DM + d];
        f32x4 c0b = *(const f32x4*)&b2[i0 * DM + d + 4];
        f32x4 c1a = *(const f32x4*)&b2[i1 * DM + d];
        f32x4 c1b = *(const f32x4*)&b2[i1 * DM + d + 4];
        f32x4 oa, ob;
        for (int i = 0; i < 4; ++i) {
            oa[i] = g0 * c0a[i] + g1 * c1a[i];
            ob[i] = g0 * c0b[i] + g1 * c1b[i];
        }
        *(f32x4*)&out[(size_t)t * DM + d]     = oa;
        *(f32x4*)&out[(size_t)t * DM + d + 4] = ob;
    }
}

// -------- compaction: deterministic hierarchical scan, no atomics --------
__global__ __launch_bounds__(1024) void compact_kernel(
    const int* __restrict__ tok_e, const float* __restrict__ tok_g,
    int* __restrict__ slot_token, float* __restrict__ slot_gate,
    int* __restrict__ eoff)
{
    __shared__ int wsum[16][NE];   // per-wave expert totals
    __shared__ int wbase[16][NE];  // per-wave exclusive bases
    __shared__ int ebl[NE];        // expert base offsets
    int tid = threadIdx.x;
    int wv = tid >> 6, lane = tid & 63;

    int ent[8];
    *(int4*)&ent[0] = *(const int4*)&tok_e[tid * 8];
    *(int4*)&ent[4] = *(const int4*)&tok_e[tid * 8 + 4];
    float gv[8];
    *(f32x4*)&gv[0] = *(const f32x4*)&tok_g[tid * 8];
    *(f32x4*)&gv[4] = *(const f32x4*)&tok_g[tid * 8 + 4];

    int cnt[NE], isc[NE];
#pragma unroll
    for (int e = 0; e < NE; ++e) {
        int c = 0;
#pragma unroll
        for (int i = 0; i < 8; ++i) c += (ent[i] == e) ? 1 : 0;
        int v = c;
#pragma unroll
        for (int off = 1; off < 64; off <<= 1) {
            int u = __shfl_up(v, off);
            if (lane >= off) v += u;
        }
        cnt[e] = c; isc[e] = v;     // isc = inclusive scan over lanes
    }
    if (lane == 63) {
#pragma unroll
        for (int e = 0; e < NE; ++e) wsum[wv][e] = isc[e];
    }
    __syncthreads();
    if (wv == 0 && lane < NE) {    // lane e owns expert e
        int e = lane, s = 0;
#pragma unroll
        for (int w = 0; w < 16; ++w) { wbase[w][e] = s; s += wsum[w][e]; }
        int til = (s + 127) >> 7;
        int rs = s, rt = til;      // 16-lane inclusive scans (rows, tiles)
#pragma unroll
        for (int off = 1; off < 16; off <<= 1) {
            int u1 = __shfl_up(rs, off);
            int u2 = __shfl_up(rt, off);
            if (lane >= off) { rs += u1; rt += u2; }
        }
        ebl[e] = rs - s;
        eoff[e] = rs - s;
        eoff[16 + e] = s;
        eoff[32 + e] = rt - til;
        if (e == NE - 1) eoff[48] = rt;
    }
    __syncthreads();
    int ofs[NE];
#pragma unroll
    for (int e = 0; e < NE; ++e)
        ofs[e] = ebl[e] + wbase[wv][e] + isc[e] - cnt[e];
#pragma unroll
    for (int i = 0; i < 8; ++i) {
        int ei = ent[i], s = 0;
#pragma unroll
        for (int e = 0; e < NE; ++e) if (ei == e) s = ofs[e];
        slot_token[s] = tid * 4 + (i >> 1);
        slot_gate[s]  = gv[i];
#pragma unroll
        for (int e = 0; e < NE; ++e) if (ei == e) ofs[e] = s + 1;
    }
}

// ------ GEMM1: h = gelu(x_bf[gather] @ w1b^T + b1) -----------------------
// LDS = exactly 32768 B (As+Bs): meta read direct from eoff (uniform scalar
// loads), tokrow held in 4 registers/thread (each thread stages the same 4
// rows every kt). Target: +1 resident block/CU vs the 34304-B version.
__global__ __launch_bounds__(256) void gemm1_kernel(
    const unsigned short* __restrict__ xb, const unsigned short* __restrict__ w1b,
    const float* __restrict__ b1, const int* __restrict__ slot_token,
    const int* __restrict__ eoff, unsigned short* __restrict__ h)
{
    __shared__ unsigned short smem[16384];     // As[128*64] + Bs[128*64]
    unsigned short* As = smem;
    unsigned short* Bs = smem + 8192;

    int tid = threadIdx.x;
    int total = eoff[48];
    int lg = xcd_chunk_logical(blockIdx.x, total * 16);
    int slot_idx = lg >> 4;
    if (slot_idx >= total) return;
    int nB = (lg & 15) * 128;
    int e = 0;
    while (e < NE - 1 && eoff[32 + e + 1] <= slot_idx) ++e;
    int mt  = slot_idx - eoff[32 + e];
    int off = eoff[e], cnt = eoff[16 + e];
    int slot0 = off + mt * 128;
    int valid = cnt - mt * 128; if (valid > 128) valid = 128;

    int wid = tid >> 6, l = tid & 63;
    int wm = (wid & 1) * 64, wn = (wid >> 1) * 64;
    int q = l >> 4, c = l & 15;

    // per-thread gather rows: row_j = wid*32 + j*8 + (l>>3), j=0..3
    int tr[4];
#pragma unroll
    for (int j = 0; j < 4; ++j) {
        int s = slot0 + wid * 32 + j * 8 + (l >> 3);
        if (s > NSLOT - 1) s = NSLOT - 1;
        tr[j] = slot_token[s];
    }

    f32x4 acc[16];
    for (int i = 0; i < 16; ++i) acc[i] = (f32x4){0.f, 0.f, 0.f, 0.f};

    const unsigned short* wb = w1b + ((size_t)e * DFF + nB) * DM;

    for (int kt = 0; kt < DM / 64; ++kt) {
#pragma unroll
        for (int j = 0; j < 4; ++j) {
            int u = (wid * 4 + j) * 64 + l;
            int row = u >> 3, sc = (u & 7) ^ (row & 7);
            gload_lds16(xb + (size_t)tr[j] * DM + kt * 64 + sc * 8, &As[u * 8]);
        }
#pragma unroll
        for (int j = 0; j < 4; ++j) {
            int u = (wid * 4 + j) * 64 + l;
            int row = u >> 3, sc = (u & 7) ^ (row & 7);
            gload_lds16(wb + (size_t)row * DM + kt * 64 + sc * 8, &Bs[u * 8]);
        }
        __syncthreads();
        for (int ks = 0; ks < 2; ++ks) {
            int sw = ((ks * 4 + q) ^ (c & 7)) * 8;
            bf16x8 af[4], bv[4];
            for (int i = 0; i < 4; ++i) af[i] = *(bf16x8*)&As[(wm + i * 16 + c) * 64 + sw];
            for (int j = 0; j < 4; ++j) bv[j] = *(bf16x8*)&Bs[(wn + j * 16 + c) * 64 + sw];
            for (int i = 0; i < 4; ++i)
                for (int j = 0; j < 4; ++j)
                    acc[i * 4 + j] = __builtin_amdgcn_mfma_f32_16x16x32_bf16(
                        af[i], bv[j], acc[i * 4 + j], 0, 0, 0);
        }
        __syncthreads();
    }

    float bias[4];
    for (int j = 0; j < 4; ++j) bias[j] = b1[e * DFF + nB + wn + j * 16 + c];
    unsigned short* bounce = smem;             // [64][136] per phase
    for (int ph = 0; ph < 2; ++ph) {
        __syncthreads();
        if ((wid & 1) == ph) {
            for (int i = 0; i < 4; ++i)
                for (int j = 0; j < 4; ++j) {
                    f32x4 a = acc[i * 4 + j];
                    for (int r = 0; r < 4; ++r) {
                        int rl = i * 16 + q * 4 + r;
                        float z = a[r] + bias[j];
                        // tanh-form GELU (~5e-4 vs erf, below bf16 quant)
                        float u2 = z * fmaf(0.0356774081f, z * z, 0.7978845608f);
                        float ex = __expf(2.0f * u2);
                        float th = 1.0f - 2.0f * __builtin_amdgcn_rcpf(ex + 1.0f);
                        float g = 0.5f * z * (1.0f + th);
                        bounce[rl * 136 + wn + j * 16 + c] = f2bf(g);
                    }
                }
        }
        __syncthreads();
        for (int it = 0; it < 4; ++it) {
            int u2 = it * 256 + tid;
            int row = u2 >> 4, ch = u2 & 15;
            int gr = ph * 64 + row;
            if (gr < valid)
                *(us8*)&h[(size_t)(slot0 + gr) * DFF + nB + ch * 8] =
                    *(us8*)&bounce[row * 136 + ch * 8];
        }
    }
}

// ------ GEMM2: split-K=KSPLIT, fused combine via gated fp32 atomics ------
// LDS = exactly 32768 B: meta via direct eoff reads; tokrow/sgate dropped
// (K-loop gathers h by slot; epilogue reads slot_token/slot_gate from L2).
__global__ __launch_bounds__(256) void gemm2_kernel(
    const unsigned short* __restrict__ h, const unsigned short* __restrict__ w2b,
    const int* __restrict__ eoff, const int* __restrict__ slot_token,
    const float* __restrict__ slot_gate, float* __restrict__ out)
{
    __shared__ unsigned short smem[16384];
    unsigned short* As = smem;
    unsigned short* Bs = smem + 8192;

    int tid = threadIdx.x;
    int total = eoff[48];
    int lg = xcd_chunk_logical(blockIdx.x, total * 16);
    int slot_idx = lg >> 4;
    if (slot_idx >= total) return;
    int nB = (lg & 3) * 128;
    int z  = (lg >> 2) & 3;                      // K-split part
    int e = 0;
    while (e < NE - 1 && eoff[32 + e + 1] <= slot_idx) ++e;
    int mt  = slot_idx - eoff[32 + e];
    int off = eoff[e], cnt = eoff[16 + e];
    int slot0 = off + mt * 128;
    int valid = cnt - mt * 128; if (valid > 128) valid = 128;

    f32x4 acc[16];
    for (int i = 0; i < 16; ++i) acc[i] = (f32x4){0.f, 0.f, 0.f, 0.f};

    const unsigned short* wb = w2b + ((size_t)e * DM + nB) * DFF
                             + (size_t)z * (DFF / KSPLIT);
    const unsigned short* hz = h + (size_t)z * (DFF / KSPLIT);
    int wid = tid >> 6, l = tid & 63;
    int wm = (wid & 1) * 64, wn = (wid >> 1) * 64;
    int q = l >> 4, c = l & 15;

    for (int kt = 0; kt < DFF / (64 * KSPLIT); ++kt) {   // 8 iters per part
#pragma unroll
        for (int j = 0; j < 4; ++j) {
            int u = (wid * 4 + j) * 64 + l;
            int row = u >> 3, sc = (u & 7) ^ (row & 7);
            size_t s = slot0 + row; if (s > NSLOT - 1) s = NSLOT - 1;
            gload_lds16(hz + s * DFF + kt * 64 + sc * 8, &As[u * 8]);
        }
#pragma unroll
        for (int j = 0; j < 4; ++j) {
            int u = (wid * 4 + j) * 64 + l;
            int row = u >> 3, sc = (u & 7) ^ (row & 7);
            gload_lds16(wb + (size_t)row * DFF + kt * 64 + sc * 8, &Bs[u * 8]);
        }
        __syncthreads();
        for (int ks = 0; ks < 2; ++ks) {
            int sw = ((ks * 4 + q) ^ (c & 7)) * 8;
            bf16x8 af[4], bv[4];
            for (int i = 0; i < 4; ++i) af[i] = *(bf16x8*)&As[(wm + i * 16 + c) * 64 + sw];
            for (int j = 0; j < 4; ++j) bv[j] = *(bf16x8*)&Bs[(wn + j * 16 + c) * 64 + sw];
            for (int i = 0; i < 4; ++i)
                for (int j = 0; j < 4; ++j)
                    acc[i * 4 + j] = __builtin_amdgcn_mfma_f32_16x16x32_bf16(
                        af[i], bv[j], acc[i * 4 + j], 0, 0, 0);
        }
        __syncthreads();
    }

    for (int i = 0; i < 4; ++i)
        for (int r = 0; r < 4; ++r) {
            int rl = wm + i * 16 + q * 4 + r;
            if (rl < valid) {
                int   tok = slot_token[slot0 + rl];
                float gt  = slot_gate [slot0 + rl];
                for (int j = 0; j < 4; ++j) {
                    int n = nB + wn + j * 16 + c;
                    atomicAdd(&out[(size_t)tok * DM + n], gt * acc[i * 4 + j][r]);
                }
            }
        }
}

extern "C" void kernel_launch(void* const* d_in, const int* in_sizes, int n_in,
                              void* d_out, int out_size, void* d_ws, size_t ws_size,
                              hipStream_t stream) {
    const float* x  = (const float*)d_in[0];
    const float* rw = (const float*)d_in[1];
    const float* rb = (const float*)d_in[2];
    const float* w1 = (const float*)d_in[3];
    const float* b1 = (const float*)d_in[4];
    const float* w2 = (const float*)d_in[5];
    const float* b2 = (const float*)d_in[6];
    float* out = (float*)d_out;

    char* ws = (char*)d_ws;
    size_t o = 0;
    unsigned short* h   = (unsigned short*)(ws + o); o += (size_t)NSLOT * DFF * 2;
    unsigned short* w1b = (unsigned short*)(ws + o); o += (size_t)NW * 2;
    unsigned short* w2b = (unsigned short*)(ws + o); o += (size_t)NW * 2;
    unsigned short* xb  = (unsigned short*)(ws + o); o += (size_t)T_TOK * DM * 2;
    int*   tok_e      = (int*)(ws + o);   o += (size_t)NSLOT * 4;
    float* tok_g      = (float*)(ws + o); o += (size_t)NSLOT * 4;
    int*   slot_token = (int*)(ws + o);   o += (size_t)NSLOT * 4;
    float* slot_gate  = (float*)(ws + o); o += (size_t)NSLOT * 4;
    int*   eoff       = (int*)(ws + o);

    convert_router_kernel<<<ROUTB + CONVB, 256, 0, stream>>>(
        w1, w2, w1b, w2b, x, rw, rb, tok_e, tok_g, xb, b2, out);
    compact_kernel<<<1, 1024, 0, stream>>>(
        tok_e, tok_g, slot_token, slot_gate, eoff);
    gemm1_kernel<<<16 * MAXTILE, 256, 0, stream>>>(
        xb, w1b, b1, slot_token, eoff, h);
    gemm2_kernel<<<4 * MAXTILE * KSPLIT, 256, 0, stream>>>(
        h, w2b, eoff, slot_token, slot_gate, out);
}

// Round 17
// 274.149 us; speedup vs baseline: 1.1248x; 1.1248x over previous
//
#include <hip/hip_runtime.h>
#include <stdint.h>

#define T_TOK 4096
#define DM    512
#define DFF   2048
#define NE    16
#define NSLOT (T_TOK * 2)
#define NW    (16 * 2048 * 512)  // 16,777,216 elems per weight tensor
#define MAXTILE 80              // max Σ ceil(cnt_e/128) = 79
#define CONVB (2 * NW / 8 / 256) // 16384 convert blocks
#define ROUTB (T_TOK / 4)        // 1024 router blocks (dispatched FIRST)
#define KSPLIT 2                 // gemm2 K-split (DFF/KSPLIT = 1024 per part)

typedef __attribute__((ext_vector_type(8))) short  bf16x8;
typedef __attribute__((ext_vector_type(4))) float  f32x4;
typedef __attribute__((ext_vector_type(8))) unsigned short us8;

static __device__ __forceinline__ unsigned short f2bf(float f) {
    unsigned int u = __float_as_uint(f);
    u += 0x7FFFu + ((u >> 16) & 1u);   // RNE
    return (unsigned short)(u >> 16);
}

static __device__ __forceinline__ void gload_lds16(const void* g, void* l) {
    __builtin_amdgcn_global_load_lds(
        (const __attribute__((address_space(1))) void*)g,
        (__attribute__((address_space(3))) void*)l, 16, 0, 0);
}

// XCD-chunked logical id (verified r8: gemm2 FETCH 106->42 MB).
static __device__ __forceinline__ int xcd_chunk_logical(int bid, int total) {
    int k = bid & 7, seq = bid >> 3;
    int q = total >> 3, r = total & 7;
    int base = k * q + (k < r ? k : r);
    int len  = q + (k < r ? 1 : 0);
    return (seq < len) ? (base + seq) : total;
}

// ---- fused prologue: [0,ROUTB) router ; [ROUTB,+CONVB) w1/w2 fp32->bf16 ----
__global__ __launch_bounds__(256) void convert_router_kernel(
    const float* __restrict__ w1, const float* __restrict__ w2,
    unsigned short* __restrict__ w1b, unsigned short* __restrict__ w2b,
    const float* __restrict__ x, const float* __restrict__ rw,
    const float* __restrict__ rb, int* __restrict__ tok_e,
    float* __restrict__ tok_g, unsigned short* __restrict__ xb)
{
    __shared__ float rws[NE * DM];
    int tid = threadIdx.x;

    if (blockIdx.x >= ROUTB) {
        // -------- convert branch ----
        size_t i = ((size_t)(blockIdx.x - ROUTB) * 256 + tid) * 8;
        const float* src; unsigned short* dst;
        if (i < (size_t)NW) { src = w1 + i;        dst = w1b + i; }
        else                { src = w2 + (i - NW); dst = w2b + (i - NW); }
        f32x4 a = __builtin_nontemporal_load((const f32x4*)src);
        f32x4 b = __builtin_nontemporal_load((const f32x4*)(src + 4));
        us8 v;
        v[0] = f2bf(a.x); v[1] = f2bf(a.y); v[2] = f2bf(a.z); v[3] = f2bf(a.w);
        v[4] = f2bf(b.x); v[5] = f2bf(b.y); v[6] = f2bf(b.z); v[7] = f2bf(b.w);
        *(us8*)dst = v;
        return;
    }

    // -------- router branch ----
    for (int i = 0; i < 8; ++i) {
        int idx = (tid + i * 256) * 4;
        *(f32x4*)&rws[idx] = *(const f32x4*)&rw[idx];
    }
    __syncthreads();

    int wid = tid >> 6, lane = tid & 63;
    int t = blockIdx.x * 4 + wid;

    float xv[8];
    const float* xp = x + (size_t)t * DM + lane * 8;
    *(f32x4*)&xv[0] = *(const f32x4*)xp;
    *(f32x4*)&xv[4] = *(const f32x4*)(xp + 4);

    us8 v;
    for (int i = 0; i < 8; ++i) v[i] = f2bf(xv[i]);
    *(us8*)&xb[(size_t)t * DM + lane * 8] = v;

    float acc[NE];
    for (int e = 0; e < NE; ++e) {
        const float* wp = &rws[e * DM + lane * 8];
        float a = 0.f;
        for (int i = 0; i < 8; ++i) a += xv[i] * wp[i];
        acc[e] = a;
    }
    for (int e = 0; e < NE; ++e) {
        float v2 = acc[e];
        for (int off = 32; off > 0; off >>= 1) v2 += __shfl_xor(v2, off);
        acc[e] = v2 + rb[e];
    }
    float m = acc[0];
    for (int e = 1; e < NE; ++e) m = fmaxf(m, acc[e]);
    float p[NE]; float s = 0.f;
    for (int e = 0; e < NE; ++e) { p[e] = expf(acc[e] - m); s += p[e]; }
    float inv = 1.f / s;
    int i0 = 0; float p0 = p[0];
    for (int e = 1; e < NE; ++e) if (p[e] > p0) { p0 = p[e]; i0 = e; }
    int i1 = (i0 == 0) ? 1 : 0; float p1 = p[i1];
    for (int e = 0; e < NE; ++e)
        if (e != i0 && p[e] > p1) { p1 = p[e]; i1 = e; }
    if (lane == 0) {
        tok_e[t * 2]     = i0;  tok_e[t * 2 + 1] = i1;
        tok_g[t * 2]     = p0 * inv;
        tok_g[t * 2 + 1] = p1 * inv;
    }
}

// -------- compaction: deterministic hierarchical scan, no atomics --------
// eoff layout: [0..15] row offset, [16..31] count, [32..47] tile_base, [48] total_tiles
// Emits slot_token (slot->token) and tok_slot (entry->slot) for combine.
__global__ __launch_bounds__(1024) void compact_kernel(
    const int* __restrict__ tok_e, int* __restrict__ slot_token,
    int* __restrict__ tok_slot, int* __restrict__ eoff)
{
    __shared__ int wsum[16][NE];   // per-wave expert totals
    __shared__ int wbase[16][NE];  // per-wave exclusive bases
    __shared__ int ebl[NE];        // expert base offsets
    int tid = threadIdx.x;
    int wv = tid >> 6, lane = tid & 63;

    int ent[8];
    *(int4*)&ent[0] = *(const int4*)&tok_e[tid * 8];
    *(int4*)&ent[4] = *(const int4*)&tok_e[tid * 8 + 4];

    int cnt[NE], isc[NE];
#pragma unroll
    for (int e = 0; e < NE; ++e) {
        int c = 0;
#pragma unroll
        for (int i = 0; i < 8; ++i) c += (ent[i] == e) ? 1 : 0;
        int v = c;
#pragma unroll
        for (int off = 1; off < 64; off <<= 1) {
            int u = __shfl_up(v, off);
            if (lane >= off) v += u;
        }
        cnt[e] = c; isc[e] = v;     // isc = inclusive scan over lanes
    }
    if (lane == 63) {
#pragma unroll
        for (int e = 0; e < NE; ++e) wsum[wv][e] = isc[e];
    }
    __syncthreads();
    if (wv == 0 && lane < NE) {    // lane e owns expert e
        int e = lane, s = 0;
#pragma unroll
        for (int w = 0; w < 16; ++w) { wbase[w][e] = s; s += wsum[w][e]; }
        int til = (s + 127) >> 7;
        int rs = s, rt = til;      // 16-lane inclusive scans (rows, tiles)
#pragma unroll
        for (int off = 1; off < 16; off <<= 1) {
            int u1 = __shfl_up(rs, off);
            int u2 = __shfl_up(rt, off);
            if (lane >= off) { rs += u1; rt += u2; }
        }
        ebl[e] = rs - s;
        eoff[e] = rs - s;
        eoff[16 + e] = s;
        eoff[32 + e] = rt - til;
        if (e == NE - 1) eoff[48] = rt;
    }
    __syncthreads();
    int ofs[NE];
#pragma unroll
    for (int e = 0; e < NE; ++e)
        ofs[e] = ebl[e] + wbase[wv][e] + isc[e] - cnt[e];
#pragma unroll
    for (int i = 0; i < 8; ++i) {
        int ei = ent[i], s = 0;
#pragma unroll
        for (int e = 0; e < NE; ++e) if (ei == e) s = ofs[e];
        slot_token[s] = tid * 4 + (i >> 1);
        tok_slot[tid * 8 + i] = s;
#pragma unroll
        for (int e = 0; e < NE; ++e) if (ei == e) ofs[e] = s + 1;
    }
}

// ------ GEMM1: h = gelu(x_bf[gather] @ w1b^T + b1), XCD-chunked 1-D grid --
__global__ __launch_bounds__(256) void gemm1_kernel(
    const unsigned short* __restrict__ xb, const unsigned short* __restrict__ w1b,
    const float* __restrict__ b1, const int* __restrict__ slot_token,
    const int* __restrict__ eoff, unsigned short* __restrict__ h)
{
    __shared__ unsigned short smem[16384];     // As[128*64] + Bs[128*64]
    __shared__ int tokrow[128];
    __shared__ int meta[49];
    unsigned short* As = smem;
    unsigned short* Bs = smem + 8192;

    int tid = threadIdx.x;
    if (tid < 49) meta[tid] = eoff[tid];
    __syncthreads();

    // logical = tile*16 + n ; 16 n-siblings of a tile share the A-tile.
    int lg = xcd_chunk_logical(blockIdx.x, meta[48] * 16);
    int slot_idx = lg >> 4;
    if (slot_idx >= meta[48]) return;
    int nB = (lg & 15) * 128;
    int e = 0;
    while (e < NE - 1 && meta[32 + e + 1] <= slot_idx) ++e;
    int mt  = slot_idx - meta[32 + e];
    int off = meta[e], cnt = meta[16 + e];
    int slot0 = off + mt * 128;
    int valid = cnt - mt * 128; if (valid > 128) valid = 128;

    if (tid < 128) {
        int s = slot0 + tid; if (s > NSLOT - 1) s = NSLOT - 1;
        tokrow[tid] = slot_token[s];
    }
    __syncthreads();

    f32x4 acc[16];
    for (int i = 0; i < 16; ++i) acc[i] = (f32x4){0.f, 0.f, 0.f, 0.f};

    const unsigned short* wb = w1b + ((size_t)e * DFF + nB) * DM;
    int wid = tid >> 6, l = tid & 63;
    int wm = (wid & 1) * 64, wn = (wid >> 1) * 64;
    int q = l >> 4, c = l & 15;

    for (int kt = 0; kt < DM / 64; ++kt) {
        for (int j = 0; j < 4; ++j) {
            int u = (wid * 4 + j) * 64 + l;
            int row = u >> 3, sc = (u & 7) ^ (row & 7);
            gload_lds16(xb + (size_t)tokrow[row] * DM + kt * 64 + sc * 8, &As[u * 8]);
        }
        for (int j = 0; j < 4; ++j) {
            int u = (wid * 4 + j) * 64 + l;
            int row = u >> 3, sc = (u & 7) ^ (row & 7);
            gload_lds16(wb + (size_t)row * DM + kt * 64 + sc * 8, &Bs[u * 8]);
        }
        __syncthreads();
        for (int ks = 0; ks < 2; ++ks) {
            int sw = ((ks * 4 + q) ^ (c & 7)) * 8;
            bf16x8 af[4], bv[4];
            for (int i = 0; i < 4; ++i) af[i] = *(bf16x8*)&As[(wm + i * 16 + c) * 64 + sw];
            for (int j = 0; j < 4; ++j) bv[j] = *(bf16x8*)&Bs[(wn + j * 16 + c) * 64 + sw];
            for (int i = 0; i < 4; ++i)
                for (int j = 0; j < 4; ++j)
                    acc[i * 4 + j] = __builtin_amdgcn_mfma_f32_16x16x32_bf16(
                        af[i], bv[j], acc[i * 4 + j], 0, 0, 0);
        }
        __syncthreads();
    }

    float bias[4];
    for (int j = 0; j < 4; ++j) bias[j] = b1[e * DFF + nB + wn + j * 16 + c];
    unsigned short* bounce = smem;             // [64][136] per phase
    for (int ph = 0; ph < 2; ++ph) {
        __syncthreads();
        if ((wid & 1) == ph) {
            for (int i = 0; i < 4; ++i)
                for (int j = 0; j < 4; ++j) {
                    f32x4 a = acc[i * 4 + j];
                    for (int r = 0; r < 4; ++r) {
                        int rl = i * 16 + q * 4 + r;
                        float z = a[r] + bias[j];
                        // tanh-form GELU (~5e-4 vs erf, below bf16 quant)
                        float u2 = z * fmaf(0.0356774081f, z * z, 0.7978845608f);
                        float ex = __expf(2.0f * u2);
                        float th = 1.0f - 2.0f * __builtin_amdgcn_rcpf(ex + 1.0f);
                        float g = 0.5f * z * (1.0f + th);
                        bounce[rl * 136 + wn + j * 16 + c] = f2bf(g);
                    }
                }
        }
        __syncthreads();
        for (int it = 0; it < 4; ++it) {
            int u2 = it * 256 + tid;
            int row = u2 >> 4, ch = u2 & 15;
            int gr = ph * 64 + row;
            if (gr < valid)
                *(us8*)&h[(size_t)(slot0 + gr) * DFF + nB + ch * 8] =
                    *(us8*)&bounce[row * 136 + ch * 8];
        }
    }
}

// ------ GEMM2: split-K=2, PLAIN STORES of fp32 partials to y[z] ----------
// No atomics: y is cached workspace; combine sums the parts. r9 showed the
// fused atomic epilogue writes through to HBM per-op (WRITE_SIZE = #atomics
// x 4B) and dominates gemm2 at ~85us.
__global__ __launch_bounds__(256) void gemm2_kernel(
    const unsigned short* __restrict__ h, const unsigned short* __restrict__ w2b,
    const int* __restrict__ eoff, float* __restrict__ y)
{
    __shared__ unsigned short smem[16384];
    __shared__ int meta[49];
    unsigned short* As = smem;
    unsigned short* Bs = smem + 8192;

    int tid = threadIdx.x;
    if (tid < 49) meta[tid] = eoff[tid];
    __syncthreads();

    // logical = tile*8 + z*4 + n ; 8 siblings share the A-tile in one L2.
    int lg = xcd_chunk_logical(blockIdx.x, meta[48] * 8);
    int slot_idx = lg >> 3;
    if (slot_idx >= meta[48]) return;
    int nB = (lg & 3) * 128;
    int z  = (lg >> 2) & 1;                      // K-split half
    int e = 0;
    while (e < NE - 1 && meta[32 + e + 1] <= slot_idx) ++e;
    int mt  = slot_idx - meta[32 + e];
    int off = meta[e], cnt = meta[16 + e];
    int slot0 = off + mt * 128;
    int valid = cnt - mt * 128; if (valid > 128) valid = 128;

    f32x4 acc[16];
    for (int i = 0; i < 16; ++i) acc[i] = (f32x4){0.f, 0.f, 0.f, 0.f};

    const unsigned short* wb = w2b + ((size_t)e * DM + nB) * DFF
                             + (size_t)z * (DFF / KSPLIT);
    const unsigned short* hz = h + (size_t)z * (DFF / KSPLIT);
    int wid = tid >> 6, l = tid & 63;
    int wm = (wid & 1) * 64, wn = (wid >> 1) * 64;
    int q = l >> 4, c = l & 15;

    for (int kt = 0; kt < DFF / (64 * KSPLIT); ++kt) {   // 16 iters per half
        for (int j = 0; j < 4; ++j) {
            int u = (wid * 4 + j) * 64 + l;
            int row = u >> 3, sc = (u & 7) ^ (row & 7);
            size_t s = slot0 + row; if (s > NSLOT - 1) s = NSLOT - 1;
            gload_lds16(hz + s * DFF + kt * 64 + sc * 8, &As[u * 8]);
        }
        for (int j = 0; j < 4; ++j) {
            int u = (wid * 4 + j) * 64 + l;
            int row = u >> 3, sc = (u & 7) ^ (row & 7);
            gload_lds16(wb + (size_t)row * DFF + kt * 64 + sc * 8, &Bs[u * 8]);
        }
        __syncthreads();
        for (int ks = 0; ks < 2; ++ks) {
            int sw = ((ks * 4 + q) ^ (c & 7)) * 8;
            bf16x8 af[4], bv[4];
            for (int i = 0; i < 4; ++i) af[i] = *(bf16x8*)&As[(wm + i * 16 + c) * 64 + sw];
            for (int j = 0; j < 4; ++j) bv[j] = *(bf16x8*)&Bs[(wn + j * 16 + c) * 64 + sw];
            for (int i = 0; i < 4; ++i)
                for (int j = 0; j < 4; ++j)
                    acc[i * 4 + j] = __builtin_amdgcn_mfma_f32_16x16x32_bf16(
                        af[i], bv[j], acc[i * 4 + j], 0, 0, 0);
        }
        __syncthreads();
    }

    float* yz = y + (size_t)z * NSLOT * DM;
    for (int i = 0; i < 4; ++i)
        for (int j = 0; j < 4; ++j) {
            int n = nB + wn + j * 16 + c;
            for (int r = 0; r < 4; ++r) {
                int rl = wm + i * 16 + q * 4 + r;
                if (rl < valid)
                    yz[(size_t)(slot0 + rl) * DM + n] = acc[i * 4 + j][r];
            }
        }
}

// ---- combine: out[t] = Σ_k g_k * (y0[s_k] + y1[s_k] + b2[e_k]) ----------
__global__ __launch_bounds__(256) void combine_kernel(
    const float* __restrict__ y, const float* __restrict__ b2,
    const int* __restrict__ tok_slot, const float* __restrict__ tok_g,
    const int* __restrict__ tok_e, float* __restrict__ out)
{
    int tid = threadIdx.x;
    int t = blockIdx.x * 2 + (tid >> 7);
    int d = (tid & 127) * 4;
    int s0 = tok_slot[t * 2], s1 = tok_slot[t * 2 + 1];
    float g0 = tok_g[t * 2], g1 = tok_g[t * 2 + 1];
    int e0 = tok_e[t * 2], e1 = tok_e[t * 2 + 1];
    const float* yB = y + (size_t)NSLOT * DM;
    f32x4 y0a = *(const f32x4*)&y [(size_t)s0 * DM + d];
    f32x4 y0b = *(const f32x4*)&yB[(size_t)s0 * DM + d];
    f32x4 y1a = *(const f32x4*)&y [(size_t)s1 * DM + d];
    f32x4 y1b = *(const f32x4*)&yB[(size_t)s1 * DM + d];
    f32x4 c0 = *(const f32x4*)&b2[e0 * DM + d];
    f32x4 c1 = *(const f32x4*)&b2[e1 * DM + d];
    f32x4 o;
    for (int i = 0; i < 4; ++i)
        o[i] = g0 * (y0a[i] + y0b[i] + c0[i]) + g1 * (y1a[i] + y1b[i] + c1[i]);
    *(f32x4*)&out[(size_t)t * DM + d] = o;
}

extern "C" void kernel_launch(void* const* d_in, const int* in_sizes, int n_in,
                              void* d_out, int out_size, void* d_ws, size_t ws_size,
                              hipStream_t stream) {
    const float* x  = (const float*)d_in[0];
    const float* rw = (const float*)d_in[1];
    const float* rb = (const float*)d_in[2];
    const float* w1 = (const float*)d_in[3];
    const float* b1 = (const float*)d_in[4];
    const float* w2 = (const float*)d_in[5];
    const float* b2 = (const float*)d_in[6];
    float* out = (float*)d_out;

    char* ws = (char*)d_ws;
    size_t o = 0;
    unsigned short* h   = (unsigned short*)(ws + o); o += (size_t)NSLOT * DFF * 2;
    unsigned short* w1b = (unsigned short*)(ws + o); o += (size_t)NW * 2;
    unsigned short* w2b = (unsigned short*)(ws + o); o += (size_t)NW * 2;
    unsigned short* xb  = (unsigned short*)(ws + o); o += (size_t)T_TOK * DM * 2;
    int*   tok_e      = (int*)(ws + o);   o += (size_t)NSLOT * 4;
    float* tok_g      = (float*)(ws + o); o += (size_t)NSLOT * 4;
    int*   tok_slot   = (int*)(ws + o);   o += (size_t)NSLOT * 4;
    int*   slot_token = (int*)(ws + o);   o += (size_t)NSLOT * 4;
    int*   eoff       = (int*)(ws + o);
    // y (2 split-K partials, 2*NSLOT*DM*4B = 32 MiB) aliases w1b (NW*2B):
    // gemm1 (last reader of w1b) completes before gemm2 writes y.
    float* y = (float*)w1b;

    convert_router_kernel<<<ROUTB + CONVB, 256, 0, stream>>>(
        w1, w2, w1b, w2b, x, rw, rb, tok_e, tok_g, xb);
    compact_kernel<<<1, 1024, 0, stream>>>(
        tok_e, slot_token, tok_slot, eoff);
    gemm1_kernel<<<16 * MAXTILE, 256, 0, stream>>>(
        xb, w1b, b1, slot_token, eoff, h);
    gemm2_kernel<<<8 * MAXTILE, 256, 0, stream>>>(
        h, w2b, eoff, y);
    combine_kernel<<<T_TOK / 2, 256, 0, stream>>>(
        y, b2, tok_slot, tok_g, tok_e, out);
}

// Round 19
// 270.704 us; speedup vs baseline: 1.1391x; 1.0127x over previous
//
#include <hip/hip_runtime.h>
#include <stdint.h>

#define T_TOK 4096
#define DM    512
#define DFF   2048
#define NE    16
#define NSLOT (T_TOK * 2)
#define NW    (16 * 2048 * 512)  // 16,777,216 elems per weight tensor
#define MAXTILE 80              // max Σ ceil(cnt_e/128) = 79
#define CONVB (2 * NW / 8 / 256) // 16384 convert blocks
#define ROUTB (T_TOK / 4)        // 1024 router blocks (dispatched FIRST)
#define KSPLIT 2                 // gemm2 K-split (DFF/KSPLIT = 1024 per part)

typedef __attribute__((ext_vector_type(8))) short  bf16x8;
typedef __attribute__((ext_vector_type(4))) float  f32x4;
typedef __attribute__((ext_vector_type(8))) unsigned short us8;

static __device__ __forceinline__ unsigned short f2bf(float f) {
    unsigned int u = __float_as_uint(f);
    u += 0x7FFFu + ((u >> 16) & 1u);   // RNE
    return (unsigned short)(u >> 16);
}

static __device__ __forceinline__ void gload_lds16(const void* g, void* l) {
    __builtin_amdgcn_global_load_lds(
        (const __attribute__((address_space(1))) void*)g,
        (__attribute__((address_space(3))) void*)l, 16, 0, 0);
}

// XCD-chunked logical id (verified r8: gemm2 FETCH 106->42 MB).
static __device__ __forceinline__ int xcd_chunk_logical(int bid, int total) {
    int k = bid & 7, seq = bid >> 3;
    int q = total >> 3, r = total & 7;
    int base = k * q + (k < r ? k : r);
    int len  = q + (k < r ? 1 : 0);
    return (seq < len) ? (base + seq) : total;
}

// ---- fused prologue: [0,ROUTB) router ; [ROUTB,+CONVB) w1/w2 fp32->bf16 ----
__global__ __launch_bounds__(256) void convert_router_kernel(
    const float* __restrict__ w1, const float* __restrict__ w2,
    unsigned short* __restrict__ w1b, unsigned short* __restrict__ w2b,
    const float* __restrict__ x, const float* __restrict__ rw,
    const float* __restrict__ rb, int* __restrict__ tok_e,
    float* __restrict__ tok_g, unsigned short* __restrict__ xb)
{
    __shared__ float rws[NE * DM];
    int tid = threadIdx.x;

    if (blockIdx.x >= ROUTB) {
        // -------- convert branch ----
        size_t i = ((size_t)(blockIdx.x - ROUTB) * 256 + tid) * 8;
        const float* src; unsigned short* dst;
        if (i < (size_t)NW) { src = w1 + i;        dst = w1b + i; }
        else                { src = w2 + (i - NW); dst = w2b + (i - NW); }
        f32x4 a = __builtin_nontemporal_load((const f32x4*)src);
        f32x4 b = __builtin_nontemporal_load((const f32x4*)(src + 4));
        us8 v;
        v[0] = f2bf(a.x); v[1] = f2bf(a.y); v[2] = f2bf(a.z); v[3] = f2bf(a.w);
        v[4] = f2bf(b.x); v[5] = f2bf(b.y); v[6] = f2bf(b.z); v[7] = f2bf(b.w);
        *(us8*)dst = v;
        return;
    }

    // -------- router branch ----
    for (int i = 0; i < 8; ++i) {
        int idx = (tid + i * 256) * 4;
        *(f32x4*)&rws[idx] = *(const f32x4*)&rw[idx];
    }
    __syncthreads();

    int wid = tid >> 6, lane = tid & 63;
    int t = blockIdx.x * 4 + wid;

    float xv[8];
    const float* xp = x + (size_t)t * DM + lane * 8;
    *(f32x4*)&xv[0] = *(const f32x4*)xp;
    *(f32x4*)&xv[4] = *(const f32x4*)(xp + 4);

    us8 v;
    for (int i = 0; i < 8; ++i) v[i] = f2bf(xv[i]);
    *(us8*)&xb[(size_t)t * DM + lane * 8] = v;

    float acc[NE];
    for (int e = 0; e < NE; ++e) {
        const float* wp = &rws[e * DM + lane * 8];
        float a = 0.f;
        for (int i = 0; i < 8; ++i) a += xv[i] * wp[i];
        acc[e] = a;
    }
    for (int e = 0; e < NE; ++e) {
        float v2 = acc[e];
        for (int off = 32; off > 0; off >>= 1) v2 += __shfl_xor(v2, off);
        acc[e] = v2 + rb[e];
    }
    float m = acc[0];
    for (int e = 1; e < NE; ++e) m = fmaxf(m, acc[e]);
    float p[NE]; float s = 0.f;
    for (int e = 0; e < NE; ++e) { p[e] = expf(acc[e] - m); s += p[e]; }
    float inv = 1.f / s;
    int i0 = 0; float p0 = p[0];
    for (int e = 1; e < NE; ++e) if (p[e] > p0) { p0 = p[e]; i0 = e; }
    int i1 = (i0 == 0) ? 1 : 0; float p1 = p[i1];
    for (int e = 0; e < NE; ++e)
        if (e != i0 && p[e] > p1) { p1 = p[e]; i1 = e; }
    if (lane == 0) {
        tok_e[t * 2]     = i0;  tok_e[t * 2 + 1] = i1;
        tok_g[t * 2]     = p0 * inv;
        tok_g[t * 2 + 1] = p1 * inv;
    }
}

// -------- compaction: deterministic hierarchical scan, no atomics --------
// eoff layout: [0..15] row offset, [16..31] count, [32..47] tile_base, [48] total_tiles
__global__ __launch_bounds__(1024) void compact_kernel(
    const int* __restrict__ tok_e, int* __restrict__ slot_token,
    int* __restrict__ tok_slot, int* __restrict__ eoff)
{
    __shared__ int wsum[16][NE];   // per-wave expert totals
    __shared__ int wbase[16][NE];  // per-wave exclusive bases
    __shared__ int ebl[NE];        // expert base offsets
    int tid = threadIdx.x;
    int wv = tid >> 6, lane = tid & 63;

    int ent[8];
    *(int4*)&ent[0] = *(const int4*)&tok_e[tid * 8];
    *(int4*)&ent[4] = *(const int4*)&tok_e[tid * 8 + 4];

    int cnt[NE], isc[NE];
#pragma unroll
    for (int e = 0; e < NE; ++e) {
        int c = 0;
#pragma unroll
        for (int i = 0; i < 8; ++i) c += (ent[i] == e) ? 1 : 0;
        int v = c;
#pragma unroll
        for (int off = 1; off < 64; off <<= 1) {
            int u = __shfl_up(v, off);
            if (lane >= off) v += u;
        }
        cnt[e] = c; isc[e] = v;     // isc = inclusive scan over lanes
    }
    if (lane == 63) {
#pragma unroll
        for (int e = 0; e < NE; ++e) wsum[wv][e] = isc[e];
    }
    __syncthreads();
    if (wv == 0 && lane < NE) {    // lane e owns expert e
        int e = lane, s = 0;
#pragma unroll
        for (int w = 0; w < 16; ++w) { wbase[w][e] = s; s += wsum[w][e]; }
        int til = (s + 127) >> 7;
        int rs = s, rt = til;      // 16-lane inclusive scans (rows, tiles)
#pragma unroll
        for (int off = 1; off < 16; off <<= 1) {
            int u1 = __shfl_up(rs, off);
            int u2 = __shfl_up(rt, off);
            if (lane >= off) { rs += u1; rt += u2; }
        }
        ebl[e] = rs - s;
        eoff[e] = rs - s;
        eoff[16 + e] = s;
        eoff[32 + e] = rt - til;
        if (e == NE - 1) eoff[48] = rt;
    }
    __syncthreads();
    int ofs[NE];
#pragma unroll
    for (int e = 0; e < NE; ++e)
        ofs[e] = ebl[e] + wbase[wv][e] + isc[e] - cnt[e];
#pragma unroll
    for (int i = 0; i < 8; ++i) {
        int ei = ent[i], s = 0;
#pragma unroll
        for (int e = 0; e < NE; ++e) if (ei == e) s = ofs[e];
        slot_token[s] = tid * 4 + (i >> 1);
        tok_slot[tid * 8 + i] = s;
#pragma unroll
        for (int e = 0; e < NE; ++e) if (ei == e) ofs[e] = s + 1;
    }
}

// ------ GEMM1: h = gelu(x_bf[gather] @ w1b^T + b1) -----------------------
// Double-buffered prefetch K-loop (T3-min): stage(kt+1) issues BEFORE the
// MFMA of kt, so HBM latency hides under compute; ONE barrier per kt
// (syncthreads drains vmcnt -> next buffer ready). Epilogue: all-wave
// j-half phases (r17 PMC: VALUBusy 34% vs MfmaUtil 13% = half-wave GELU
// was 2x its work wall-time).
__global__ __launch_bounds__(256) void gemm1_kernel(
    const unsigned short* __restrict__ xb, const unsigned short* __restrict__ w1b,
    const float* __restrict__ b1, const int* __restrict__ slot_token,
    const int* __restrict__ eoff, unsigned short* __restrict__ h)
{
    __shared__ unsigned short smem[32768];     // 2 x (As[8192] + Bs[8192])
    __shared__ int tokrow[128];
    __shared__ int meta[49];

    int tid = threadIdx.x;
    if (tid < 49) meta[tid] = eoff[tid];
    __syncthreads();

    // logical = tile*16 + n ; 16 n-siblings of a tile share the A-tile.
    int lg = xcd_chunk_logical(blockIdx.x, meta[48] * 16);
    int slot_idx = lg >> 4;
    if (slot_idx >= meta[48]) return;
    int nB = (lg & 15) * 128;
    int e = 0;
    while (e < NE - 1 && meta[32 + e + 1] <= slot_idx) ++e;
    int mt  = slot_idx - meta[32 + e];
    int off = meta[e], cnt = meta[16 + e];
    int slot0 = off + mt * 128;
    int valid = cnt - mt * 128; if (valid > 128) valid = 128;

    if (tid < 128) {
        int s = slot0 + tid; if (s > NSLOT - 1) s = NSLOT - 1;
        tokrow[tid] = slot_token[s];
    }
    __syncthreads();

    f32x4 acc[16];
    for (int i = 0; i < 16; ++i) acc[i] = (f32x4){0.f, 0.f, 0.f, 0.f};

    const unsigned short* wb = w1b + ((size_t)e * DFF + nB) * DM;
    int wid = tid >> 6, l = tid & 63;
    int wm = (wid & 1) * 64, wn = (wid >> 1) * 64;
    int q = l >> 4, c = l & 15;

    auto stage = [&](int buf, int kt) {
        unsigned short* A = &smem[buf * 16384];
        unsigned short* B = A + 8192;
        for (int j = 0; j < 4; ++j) {
            int u = (wid * 4 + j) * 64 + l;
            int row = u >> 3, sc = (u & 7) ^ (row & 7);
            gload_lds16(xb + (size_t)tokrow[row] * DM + kt * 64 + sc * 8, &A[u * 8]);
        }
        for (int j = 0; j < 4; ++j) {
            int u = (wid * 4 + j) * 64 + l;
            int row = u >> 3, sc = (u & 7) ^ (row & 7);
            gload_lds16(wb + (size_t)row * DM + kt * 64 + sc * 8, &B[u * 8]);
        }
    };

    stage(0, 0);
    __syncthreads();                       // vmcnt(0) drain: buf0 ready
    int cur = 0;
    for (int kt = 0; kt < DM / 64; ++kt) {
        if (kt + 1 < DM / 64) stage(cur ^ 1, kt + 1);   // prefetch next tile
        unsigned short* A = &smem[cur * 16384];
        unsigned short* B = A + 8192;
        for (int ks = 0; ks < 2; ++ks) {
            int sw = ((ks * 4 + q) ^ (c & 7)) * 8;
            bf16x8 af[4], bv[4];
            for (int i = 0; i < 4; ++i) af[i] = *(bf16x8*)&A[(wm + i * 16 + c) * 64 + sw];
            for (int j = 0; j < 4; ++j) bv[j] = *(bf16x8*)&B[(wn + j * 16 + c) * 64 + sw];
            for (int i = 0; i < 4; ++i)
                for (int j = 0; j < 4; ++j)
                    acc[i * 4 + j] = __builtin_amdgcn_mfma_f32_16x16x32_bf16(
                        af[i], bv[j], acc[i * 4 + j], 0, 0, 0);
        }
        __syncthreads();                   // next buf ready + cur reads done
        cur ^= 1;
    }

    float bias[4];
    for (int j = 0; j < 4; ++j) bias[j] = b1[e * DFF + nB + wn + j * 16 + c];
    // all-wave epilogue: phase ph covers j in {2ph,2ph+1} -> 64 h-cols
    // (strips [32ph,32ph+32) and [64+32ph,96+32ph)); bounce [128][80].
    unsigned short* bounce = smem;
    for (int ph = 0; ph < 2; ++ph) {
        __syncthreads();
        for (int jj = 0; jj < 2; ++jj) {
            int j = 2 * ph + jj;
            for (int i = 0; i < 4; ++i) {
                f32x4 a = acc[i * 4 + j];
                for (int r = 0; r < 4; ++r) {
                    int rl = wm + i * 16 + q * 4 + r;
                    float z = a[r] + bias[j];
                    // tanh-form GELU (~5e-4 vs erf, below bf16 quant)
                    float u2 = z * fmaf(0.0356774081f, z * z, 0.7978845608f);
                    float ex = __expf(2.0f * u2);
                    float th = 1.0f - 2.0f * __builtin_amdgcn_rcpf(ex + 1.0f);
                    float g = 0.5f * z * (1.0f + th);
                    bounce[rl * 80 + (wn >> 1) + jj * 16 + c] = f2bf(g);
                }
            }
        }
        __syncthreads();
        for (int it = 0; it < 4; ++it) {
            int u2 = it * 256 + tid;
            int row = u2 >> 3, ch = u2 & 7;
            int cl = ch * 8;                       // local col 0..56
            int n  = (cl < 32 ? cl : 32 + cl) + 32 * ph;
            if (row < valid)
                *(us8*)&h[(size_t)(slot0 + row) * DFF + nB + n] =
                    *(us8*)&bounce[row * 80 + cl];
        }
    }
}

// ------ GEMM2: split-K=2, dbuf prefetch K-loop, plain stores to y[z] -----
__global__ __launch_bounds__(256) void gemm2_kernel(
    const unsigned short* __restrict__ h, const unsigned short* __restrict__ w2b,
    const int* __restrict__ eoff, float* __restrict__ y)
{
    __shared__ unsigned short smem[32768];     // 2 x (As[8192] + Bs[8192])
    __shared__ int meta[49];

    int tid = threadIdx.x;
    if (tid < 49) meta[tid] = eoff[tid];
    __syncthreads();

    // logical = tile*8 + z*4 + n ; 8 siblings share the A-tile in one L2.
    int lg = xcd_chunk_logical(blockIdx.x, meta[48] * 8);
    int slot_idx = lg >> 3;
    if (slot_idx >= meta[48]) return;
    int nB = (lg & 3) * 128;
    int z  = (lg >> 2) & 1;                      // K-split half
    int e = 0;
    while (e < NE - 1 && meta[32 + e + 1] <= slot_idx) ++e;
    int mt  = slot_idx - meta[32 + e];
    int off = meta[e], cnt = meta[16 + e];
    int slot0 = off + mt * 128;
    int valid = cnt - mt * 128; if (valid > 128) valid = 128;

    f32x4 acc[16];
    for (int i = 0; i < 16; ++i) acc[i] = (f32x4){0.f, 0.f, 0.f, 0.f};

    const unsigned short* wb = w2b + ((size_t)e * DM + nB) * DFF
                             + (size_t)z * (DFF / KSPLIT);
    const unsigned short* hz = h + (size_t)z * (DFF / KSPLIT);
    int wid = tid >> 6, l = tid & 63;
    int wm = (wid & 1) * 64, wn = (wid >> 1) * 64;
    int q = l >> 4, c = l & 15;

    auto stage = [&](int buf, int kt) {
        unsigned short* A = &smem[buf * 16384];
        unsigned short* B = A + 8192;
        for (int j = 0; j < 4; ++j) {
            int u = (wid * 4 + j) * 64 + l;
            int row = u >> 3, sc = (u & 7) ^ (row & 7);
            size_t s = slot0 + row; if (s > NSLOT - 1) s = NSLOT - 1;
            gload_lds16(hz + s * DFF + kt * 64 + sc * 8, &A[u * 8]);
        }
        for (int j = 0; j < 4; ++j) {
            int u = (wid * 4 + j) * 64 + l;
            int row = u >> 3, sc = (u & 7) ^ (row & 7);
            gload_lds16(wb + (size_t)row * DFF + kt * 64 + sc * 8, &B[u * 8]);
        }
    };

    const int NT = DFF / (64 * KSPLIT);        // 16 iters per half
    stage(0, 0);
    __syncthreads();
    int cur = 0;
    for (int kt = 0; kt < NT; ++kt) {
        if (kt + 1 < NT) stage(cur ^ 1, kt + 1);
        unsigned short* A = &smem[cur * 16384];
        unsigned short* B = A + 8192;
        for (int ks = 0; ks < 2; ++ks) {
            int sw = ((ks * 4 + q) ^ (c & 7)) * 8;
            bf16x8 af[4], bv[4];
            for (int i = 0; i < 4; ++i) af[i] = *(bf16x8*)&A[(wm + i * 16 + c) * 64 + sw];
            for (int j = 0; j < 4; ++j) bv[j] = *(bf16x8*)&B[(wn + j * 16 + c) * 64 + sw];
            for (int i = 0; i < 4; ++i)
                for (int j = 0; j < 4; ++j)
                    acc[i * 4 + j] = __builtin_amdgcn_mfma_f32_16x16x32_bf16(
                        af[i], bv[j], acc[i * 4 + j], 0, 0, 0);
        }
        __syncthreads();
        cur ^= 1;
    }

    float* yz = y + (size_t)z * NSLOT * DM;
    for (int i = 0; i < 4; ++i)
        for (int j = 0; j < 4; ++j) {
            int n = nB + wn + j * 16 + c;
            for (int r = 0; r < 4; ++r) {
                int rl = wm + i * 16 + q * 4 + r;
                if (rl < valid)
                    yz[(size_t)(slot0 + rl) * DM + n] = acc[i * 4 + j][r];
            }
        }
}

// ---- combine: out[t] = Σ_k g_k * (y0[s_k] + y1[s_k] + b2[e_k]) ----------
__global__ __launch_bounds__(256) void combine_kernel(
    const float* __restrict__ y, const float* __restrict__ b2,
    const int* __restrict__ tok_slot, const float* __restrict__ tok_g,
    const int* __restrict__ tok_e, float* __restrict__ out)
{
    int tid = threadIdx.x;
    int t = blockIdx.x * 2 + (tid >> 7);
    int d = (tid & 127) * 4;
    int s0 = tok_slot[t * 2], s1 = tok_slot[t * 2 + 1];
    float g0 = tok_g[t * 2], g1 = tok_g[t * 2 + 1];
    int e0 = tok_e[t * 2], e1 = tok_e[t * 2 + 1];
    const float* yB = y + (size_t)NSLOT * DM;
    f32x4 y0a = *(const f32x4*)&y [(size_t)s0 * DM + d];
    f32x4 y0b = *(const f32x4*)&yB[(size_t)s0 * DM + d];
    f32x4 y1a = *(const f32x4*)&y [(size_t)s1 * DM + d];
    f32x4 y1b = *(const f32x4*)&yB[(size_t)s1 * DM + d];
    f32x4 c0 = *(const f32x4*)&b2[e0 * DM + d];
    f32x4 c1 = *(const f32x4*)&b2[e1 * DM + d];
    f32x4 o;
    for (int i = 0; i < 4; ++i)
        o[i] = g0 * (y0a[i] + y0b[i] + c0[i]) + g1 * (y1a[i] + y1b[i] + c1[i]);
    *(f32x4*)&out[(size_t)t * DM + d] = o;
}

extern "C" void kernel_launch(void* const* d_in, const int* in_sizes, int n_in,
                              void* d_out, int out_size, void* d_ws, size_t ws_size,
                              hipStream_t stream) {
    const float* x  = (const float*)d_in[0];
    const float* rw = (const float*)d_in[1];
    const float* rb = (const float*)d_in[2];
    const float* w1 = (const float*)d_in[3];
    const float* b1 = (const float*)d_in[4];
    const float* w2 = (const float*)d_in[5];
    const float* b2 = (const float*)d_in[6];
    float* out = (float*)d_out;

    char* ws = (char*)d_ws;
    size_t o = 0;
    unsigned short* h   = (unsigned short*)(ws + o); o += (size_t)NSLOT * DFF * 2;
    unsigned short* w1b = (unsigned short*)(ws + o); o += (size_t)NW * 2;
    unsigned short* w2b = (unsigned short*)(ws + o); o += (size_t)NW * 2;
    unsigned short* xb  = (unsigned short*)(ws + o); o += (size_t)T_TOK * DM * 2;
    int*   tok_e      = (int*)(ws + o);   o += (size_t)NSLOT * 4;
    float* tok_g      = (float*)(ws + o); o += (size_t)NSLOT * 4;
    int*   tok_slot   = (int*)(ws + o);   o += (size_t)NSLOT * 4;
    int*   slot_token = (int*)(ws + o);   o += (size_t)NSLOT * 4;
    int*   eoff       = (int*)(ws + o);
    // y (2 split-K partials, 2*NSLOT*DM*4B = 32 MiB) aliases w1b (NW*2B):
    // gemm1 (last reader of w1b) completes before gemm2 writes y.
    float* y = (float*)w1b;

    convert_router_kernel<<<ROUTB + CONVB, 256, 0, stream>>>(
        w1, w2, w1b, w2b, x, rw, rb, tok_e, tok_g, xb);
    compact_kernel<<<1, 1024, 0, stream>>>(
        tok_e, slot_token, tok_slot, eoff);
    gemm1_kernel<<<16 * MAXTILE, 256, 0, stream>>>(
        xb, w1b, b1, slot_token, eoff, h);
    gemm2_kernel<<<8 * MAXTILE, 256, 0, stream>>>(
        h, w2b, eoff, y);
    combine_kernel<<<T_TOK / 2, 256, 0, stream>>>(
        y, b2, tok_slot, tok_g, tok_e, out);
}

// Round 20
// 267.289 us; speedup vs baseline: 1.1536x; 1.0128x over previous
//
#include <hip/hip_runtime.h>
#include <stdint.h>

#define T_TOK 4096
#define DM    512
#define DFF   2048
#define NE    16
#define NSLOT (T_TOK * 2)
#define NW    (16 * 2048 * 512)  // 16,777,216 elems per weight tensor
#define MAXTILE 80              // max Σ ceil(cnt_e/128) = 79
#define CONVB 4096               // convert blocks; each handles 8192 elems
#define ROUTB (T_TOK / 4)        // 1024 router blocks (dispatched FIRST)
#define KSPLIT 2                 // gemm2 K-split (DFF/KSPLIT = 1024 per part)

typedef __attribute__((ext_vector_type(8))) short  bf16x8;
typedef __attribute__((ext_vector_type(4))) float  f32x4;
typedef __attribute__((ext_vector_type(8))) unsigned short us8;

static __device__ __forceinline__ unsigned short f2bf(float f) {
    unsigned int u = __float_as_uint(f);
    u += 0x7FFFu + ((u >> 16) & 1u);   // RNE
    return (unsigned short)(u >> 16);
}

static __device__ __forceinline__ void gload_lds16(const void* g, void* l) {
    __builtin_amdgcn_global_load_lds(
        (const __attribute__((address_space(1))) void*)g,
        (__attribute__((address_space(3))) void*)l, 16, 0, 0);
}

// XCD-chunked logical id (verified r8: gemm2 FETCH 106->42 MB).
static __device__ __forceinline__ int xcd_chunk_logical(int bid, int total) {
    int k = bid & 7, seq = bid >> 3;
    int q = total >> 3, r = total & 7;
    int base = k * q + (k < r ? k : r);
    int len  = q + (k < r ? 1 : 0);
    return (seq < len) ? (base + seq) : total;
}

// ---- fused prologue: [0,ROUTB) router ; [ROUTB,+CONVB) w1/w2 fp32->bf16 ----
// r19 PMC: 17408 tiny convert blocks retired at only 348 blocks/us with
// OccupancyPercent 26% and 2.8 TB/s -> dispatch-rate-bound, not BW-bound.
// Fix: 4x fatter convert blocks (8192 elems each, 4 unrolled chunks).
__global__ __launch_bounds__(256) void convert_router_kernel(
    const float* __restrict__ w1, const float* __restrict__ w2,
    unsigned short* __restrict__ w1b, unsigned short* __restrict__ w2b,
    const float* __restrict__ x, const float* __restrict__ rw,
    const float* __restrict__ rb, int* __restrict__ tok_e,
    float* __restrict__ tok_g, unsigned short* __restrict__ xb)
{
    __shared__ float rws[NE * DM];
    int tid = threadIdx.x;

    if (blockIdx.x >= ROUTB) {
        // -------- convert branch: contiguous 8192-elem region per block ----
        // NW % 8192 == 0 -> a region never straddles the w1/w2 boundary.
        size_t base = (size_t)(blockIdx.x - ROUTB) * 8192;
        const float* src; unsigned short* dst;
        if (base < (size_t)NW) { src = w1 + base;        dst = w1b + base; }
        else                   { src = w2 + (base - NW); dst = w2b + (base - NW); }
#pragma unroll
        for (int it = 0; it < 4; ++it) {
            int off2 = it * 2048 + tid * 8;
            f32x4 a = __builtin_nontemporal_load((const f32x4*)(src + off2));
            f32x4 b = __builtin_nontemporal_load((const f32x4*)(src + off2 + 4));
            us8 v;
            v[0] = f2bf(a.x); v[1] = f2bf(a.y); v[2] = f2bf(a.z); v[3] = f2bf(a.w);
            v[4] = f2bf(b.x); v[5] = f2bf(b.y); v[6] = f2bf(b.z); v[7] = f2bf(b.w);
            *(us8*)(dst + off2) = v;
        }
        return;
    }

    // -------- router branch (byte-identical to r17/r19-verified) ----
    for (int i = 0; i < 8; ++i) {
        int idx = (tid + i * 256) * 4;
        *(f32x4*)&rws[idx] = *(const f32x4*)&rw[idx];
    }
    __syncthreads();

    int wid = tid >> 6, lane = tid & 63;
    int t = blockIdx.x * 4 + wid;

    float xv[8];
    const float* xp = x + (size_t)t * DM + lane * 8;
    *(f32x4*)&xv[0] = *(const f32x4*)xp;
    *(f32x4*)&xv[4] = *(const f32x4*)(xp + 4);

    us8 v;
    for (int i = 0; i < 8; ++i) v[i] = f2bf(xv[i]);
    *(us8*)&xb[(size_t)t * DM + lane * 8] = v;

    float acc[NE];
    for (int e = 0; e < NE; ++e) {
        const float* wp = &rws[e * DM + lane * 8];
        float a = 0.f;
        for (int i = 0; i < 8; ++i) a += xv[i] * wp[i];
        acc[e] = a;
    }
    for (int e = 0; e < NE; ++e) {
        float v2 = acc[e];
        for (int off = 32; off > 0; off >>= 1) v2 += __shfl_xor(v2, off);
        acc[e] = v2 + rb[e];
    }
    float m = acc[0];
    for (int e = 1; e < NE; ++e) m = fmaxf(m, acc[e]);
    float p[NE]; float s = 0.f;
    for (int e = 0; e < NE; ++e) { p[e] = expf(acc[e] - m); s += p[e]; }
    float inv = 1.f / s;
    int i0 = 0; float p0 = p[0];
    for (int e = 1; e < NE; ++e) if (p[e] > p0) { p0 = p[e]; i0 = e; }
    int i1 = (i0 == 0) ? 1 : 0; float p1 = p[i1];
    for (int e = 0; e < NE; ++e)
        if (e != i0 && p[e] > p1) { p1 = p[e]; i1 = e; }
    if (lane == 0) {
        tok_e[t * 2]     = i0;  tok_e[t * 2 + 1] = i1;
        tok_g[t * 2]     = p0 * inv;
        tok_g[t * 2 + 1] = p1 * inv;
    }
}

// -------- compaction: deterministic hierarchical scan, no atomics --------
// eoff layout: [0..15] row offset, [16..31] count, [32..47] tile_base, [48] total_tiles
__global__ __launch_bounds__(1024) void compact_kernel(
    const int* __restrict__ tok_e, int* __restrict__ slot_token,
    int* __restrict__ tok_slot, int* __restrict__ eoff)
{
    __shared__ int wsum[16][NE];   // per-wave expert totals
    __shared__ int wbase[16][NE];  // per-wave exclusive bases
    __shared__ int ebl[NE];        // expert base offsets
    int tid = threadIdx.x;
    int wv = tid >> 6, lane = tid & 63;

    int ent[8];
    *(int4*)&ent[0] = *(const int4*)&tok_e[tid * 8];
    *(int4*)&ent[4] = *(const int4*)&tok_e[tid * 8 + 4];

    int cnt[NE], isc[NE];
#pragma unroll
    for (int e = 0; e < NE; ++e) {
        int c = 0;
#pragma unroll
        for (int i = 0; i < 8; ++i) c += (ent[i] == e) ? 1 : 0;
        int v = c;
#pragma unroll
        for (int off = 1; off < 64; off <<= 1) {
            int u = __shfl_up(v, off);
            if (lane >= off) v += u;
        }
        cnt[e] = c; isc[e] = v;     // isc = inclusive scan over lanes
    }
    if (lane == 63) {
#pragma unroll
        for (int e = 0; e < NE; ++e) wsum[wv][e] = isc[e];
    }
    __syncthreads();
    if (wv == 0 && lane < NE) {    // lane e owns expert e
        int e = lane, s = 0;
#pragma unroll
        for (int w = 0; w < 16; ++w) { wbase[w][e] = s; s += wsum[w][e]; }
        int til = (s + 127) >> 7;
        int rs = s, rt = til;      // 16-lane inclusive scans (rows, tiles)
#pragma unroll
        for (int off = 1; off < 16; off <<= 1) {
            int u1 = __shfl_up(rs, off);
            int u2 = __shfl_up(rt, off);
            if (lane >= off) { rs += u1; rt += u2; }
        }
        ebl[e] = rs - s;
        eoff[e] = rs - s;
        eoff[16 + e] = s;
        eoff[32 + e] = rt - til;
        if (e == NE - 1) eoff[48] = rt;
    }
    __syncthreads();
    int ofs[NE];
#pragma unroll
    for (int e = 0; e < NE; ++e)
        ofs[e] = ebl[e] + wbase[wv][e] + isc[e] - cnt[e];
#pragma unroll
    for (int i = 0; i < 8; ++i) {
        int ei = ent[i], s = 0;
#pragma unroll
        for (int e = 0; e < NE; ++e) if (ei == e) s = ofs[e];
        slot_token[s] = tid * 4 + (i >> 1);
        tok_slot[tid * 8 + i] = s;
#pragma unroll
        for (int e = 0; e < NE; ++e) if (ei == e) ofs[e] = s + 1;
    }
}

// ------ GEMM1: h = gelu(x_bf[gather] @ w1b^T + b1) -----------------------
// Double-buffered prefetch K-loop; all-wave j-half epilogue (r19-verified).
__global__ __launch_bounds__(256) void gemm1_kernel(
    const unsigned short* __restrict__ xb, const unsigned short* __restrict__ w1b,
    const float* __restrict__ b1, const int* __restrict__ slot_token,
    const int* __restrict__ eoff, unsigned short* __restrict__ h)
{
    __shared__ unsigned short smem[32768];     // 2 x (As[8192] + Bs[8192])
    __shared__ int tokrow[128];
    __shared__ int meta[49];

    int tid = threadIdx.x;
    if (tid < 49) meta[tid] = eoff[tid];
    __syncthreads();

    // logical = tile*16 + n ; 16 n-siblings of a tile share the A-tile.
    int lg = xcd_chunk_logical(blockIdx.x, meta[48] * 16);
    int slot_idx = lg >> 4;
    if (slot_idx >= meta[48]) return;
    int nB = (lg & 15) * 128;
    int e = 0;
    while (e < NE - 1 && meta[32 + e + 1] <= slot_idx) ++e;
    int mt  = slot_idx - meta[32 + e];
    int off = meta[e], cnt = meta[16 + e];
    int slot0 = off + mt * 128;
    int valid = cnt - mt * 128; if (valid > 128) valid = 128;

    if (tid < 128) {
        int s = slot0 + tid; if (s > NSLOT - 1) s = NSLOT - 1;
        tokrow[tid] = slot_token[s];
    }
    __syncthreads();

    f32x4 acc[16];
    for (int i = 0; i < 16; ++i) acc[i] = (f32x4){0.f, 0.f, 0.f, 0.f};

    const unsigned short* wb = w1b + ((size_t)e * DFF + nB) * DM;
    int wid = tid >> 6, l = tid & 63;
    int wm = (wid & 1) * 64, wn = (wid >> 1) * 64;
    int q = l >> 4, c = l & 15;

    auto stage = [&](int buf, int kt) {
        unsigned short* A = &smem[buf * 16384];
        unsigned short* B = A + 8192;
        for (int j = 0; j < 4; ++j) {
            int u = (wid * 4 + j) * 64 + l;
            int row = u >> 3, sc = (u & 7) ^ (row & 7);
            gload_lds16(xb + (size_t)tokrow[row] * DM + kt * 64 + sc * 8, &A[u * 8]);
        }
        for (int j = 0; j < 4; ++j) {
            int u = (wid * 4 + j) * 64 + l;
            int row = u >> 3, sc = (u & 7) ^ (row & 7);
            gload_lds16(wb + (size_t)row * DM + kt * 64 + sc * 8, &B[u * 8]);
        }
    };

    stage(0, 0);
    __syncthreads();                       // vmcnt(0) drain: buf0 ready
    int cur = 0;
    for (int kt = 0; kt < DM / 64; ++kt) {
        if (kt + 1 < DM / 64) stage(cur ^ 1, kt + 1);   // prefetch next tile
        unsigned short* A = &smem[cur * 16384];
        unsigned short* B = A + 8192;
        for (int ks = 0; ks < 2; ++ks) {
            int sw = ((ks * 4 + q) ^ (c & 7)) * 8;
            bf16x8 af[4], bv[4];
            for (int i = 0; i < 4; ++i) af[i] = *(bf16x8*)&A[(wm + i * 16 + c) * 64 + sw];
            for (int j = 0; j < 4; ++j) bv[j] = *(bf16x8*)&B[(wn + j * 16 + c) * 64 + sw];
            for (int i = 0; i < 4; ++i)
                for (int j = 0; j < 4; ++j)
                    acc[i * 4 + j] = __builtin_amdgcn_mfma_f32_16x16x32_bf16(
                        af[i], bv[j], acc[i * 4 + j], 0, 0, 0);
        }
        __syncthreads();                   // next buf ready + cur reads done
        cur ^= 1;
    }

    float bias[4];
    for (int j = 0; j < 4; ++j) bias[j] = b1[e * DFF + nB + wn + j * 16 + c];
    // all-wave epilogue: phase ph covers j in {2ph,2ph+1} -> 64 h-cols
    // (strips [32ph,32ph+32) and [64+32ph,96+32ph)); bounce [128][80].
    unsigned short* bounce = smem;
    for (int ph = 0; ph < 2; ++ph) {
        __syncthreads();
        for (int jj = 0; jj < 2; ++jj) {
            int j = 2 * ph + jj;
            for (int i = 0; i < 4; ++i) {
                f32x4 a = acc[i * 4 + j];
                for (int r = 0; r < 4; ++r) {
                    int rl = wm + i * 16 + q * 4 + r;
                    float z = a[r] + bias[j];
                    // tanh-form GELU (~5e-4 vs erf, below bf16 quant)
                    float u2 = z * fmaf(0.0356774081f, z * z, 0.7978845608f);
                    float ex = __expf(2.0f * u2);
                    float th = 1.0f - 2.0f * __builtin_amdgcn_rcpf(ex + 1.0f);
                    float g = 0.5f * z * (1.0f + th);
                    bounce[rl * 80 + (wn >> 1) + jj * 16 + c] = f2bf(g);
                }
            }
        }
        __syncthreads();
        for (int it = 0; it < 4; ++it) {
            int u2 = it * 256 + tid;
            int row = u2 >> 3, ch = u2 & 7;
            int cl = ch * 8;                       // local col 0..56
            int n  = (cl < 32 ? cl : 32 + cl) + 32 * ph;
            if (row < valid)
                *(us8*)&h[(size_t)(slot0 + row) * DFF + nB + n] =
                    *(us8*)&bounce[row * 80 + cl];
        }
    }
}

// ------ GEMM2: split-K=2, dbuf prefetch K-loop, plain stores to y[z] -----
__global__ __launch_bounds__(256) void gemm2_kernel(
    const unsigned short* __restrict__ h, const unsigned short* __restrict__ w2b,
    const int* __restrict__ eoff, float* __restrict__ y)
{
    __shared__ unsigned short smem[32768];     // 2 x (As[8192] + Bs[8192])
    __shared__ int meta[49];

    int tid = threadIdx.x;
    if (tid < 49) meta[tid] = eoff[tid];
    __syncthreads();

    // logical = tile*8 + z*4 + n ; 8 siblings share the A-tile in one L2.
    int lg = xcd_chunk_logical(blockIdx.x, meta[48] * 8);
    int slot_idx = lg >> 3;
    if (slot_idx >= meta[48]) return;
    int nB = (lg & 3) * 128;
    int z  = (lg >> 2) & 1;                      // K-split half
    int e = 0;
    while (e < NE - 1 && meta[32 + e + 1] <= slot_idx) ++e;
    int mt  = slot_idx - meta[32 + e];
    int off = meta[e], cnt = meta[16 + e];
    int slot0 = off + mt * 128;
    int valid = cnt - mt * 128; if (valid > 128) valid = 128;

    f32x4 acc[16];
    for (int i = 0; i < 16; ++i) acc[i] = (f32x4){0.f, 0.f, 0.f, 0.f};

    const unsigned short* wb = w2b + ((size_t)e * DM + nB) * DFF
                             + (size_t)z * (DFF / KSPLIT);
    const unsigned short* hz = h + (size_t)z * (DFF / KSPLIT);
    int wid = tid >> 6, l = tid & 63;
    int wm = (wid & 1) * 64, wn = (wid >> 1) * 64;
    int q = l >> 4, c = l & 15;

    auto stage = [&](int buf, int kt) {
        unsigned short* A = &smem[buf * 16384];
        unsigned short* B = A + 8192;
        for (int j = 0; j < 4; ++j) {
            int u = (wid * 4 + j) * 64 + l;
            int row = u >> 3, sc = (u & 7) ^ (row & 7);
            size_t s = slot0 + row; if (s > NSLOT - 1) s = NSLOT - 1;
            gload_lds16(hz + s * DFF + kt * 64 + sc * 8, &A[u * 8]);
        }
        for (int j = 0; j < 4; ++j) {
            int u = (wid * 4 + j) * 64 + l;
            int row = u >> 3, sc = (u & 7) ^ (row & 7);
            gload_lds16(wb + (size_t)row * DFF + kt * 64 + sc * 8, &B[u * 8]);
        }
    };

    const int NT = DFF / (64 * KSPLIT);        // 16 iters per half
    stage(0, 0);
    __syncthreads();
    int cur = 0;
    for (int kt = 0; kt < NT; ++kt) {
        if (kt + 1 < NT) stage(cur ^ 1, kt + 1);
        unsigned short* A = &smem[cur * 16384];
        unsigned short* B = A + 8192;
        for (int ks = 0; ks < 2; ++ks) {
            int sw = ((ks * 4 + q) ^ (c & 7)) * 8;
            bf16x8 af[4], bv[4];
            for (int i = 0; i < 4; ++i) af[i] = *(bf16x8*)&A[(wm + i * 16 + c) * 64 + sw];
            for (int j = 0; j < 4; ++j) bv[j] = *(bf16x8*)&B[(wn + j * 16 + c) * 64 + sw];
            for (int i = 0; i < 4; ++i)
                for (int j = 0; j < 4; ++j)
                    acc[i * 4 + j] = __builtin_amdgcn_mfma_f32_16x16x32_bf16(
                        af[i], bv[j], acc[i * 4 + j], 0, 0, 0);
        }
        __syncthreads();
        cur ^= 1;
    }

    float* yz = y + (size_t)z * NSLOT * DM;
    for (int i = 0; i < 4; ++i)
        for (int j = 0; j < 4; ++j) {
            int n = nB + wn + j * 16 + c;
            for (int r = 0; r < 4; ++r) {
                int rl = wm + i * 16 + q * 4 + r;
                if (rl < valid)
                    yz[(size_t)(slot0 + rl) * DM + n] = acc[i * 4 + j][r];
            }
        }
}

// ---- combine: out[t] = Σ_k g_k * (y0[s_k] + y1[s_k] + b2[e_k]) ----------
__global__ __launch_bounds__(256) void combine_kernel(
    const float* __restrict__ y, const float* __restrict__ b2,
    const int* __restrict__ tok_slot, const float* __restrict__ tok_g,
    const int* __restrict__ tok_e, float* __restrict__ out)
{
    int tid = threadIdx.x;
    int t = blockIdx.x * 2 + (tid >> 7);
    int d = (tid & 127) * 4;
    int s0 = tok_slot[t * 2], s1 = tok_slot[t * 2 + 1];
    float g0 = tok_g[t * 2], g1 = tok_g[t * 2 + 1];
    int e0 = tok_e[t * 2], e1 = tok_e[t * 2 + 1];
    const float* yB = y + (size_t)NSLOT * DM;
    f32x4 y0a = *(const f32x4*)&y [(size_t)s0 * DM + d];
    f32x4 y0b = *(const f32x4*)&yB[(size_t)s0 * DM + d];
    f32x4 y1a = *(const f32x4*)&y [(size_t)s1 * DM + d];
    f32x4 y1b = *(const f32x4*)&yB[(size_t)s1 * DM + d];
    f32x4 c0 = *(const f32x4*)&b2[e0 * DM + d];
    f32x4 c1 = *(const f32x4*)&b2[e1 * DM + d];
    f32x4 o;
    for (int i = 0; i < 4; ++i)
        o[i] = g0 * (y0a[i] + y0b[i] + c0[i]) + g1 * (y1a[i] + y1b[i] + c1[i]);
    *(f32x4*)&out[(size_t)t * DM + d] = o;
}

extern "C" void kernel_launch(void* const* d_in, const int* in_sizes, int n_in,
                              void* d_out, int out_size, void* d_ws, size_t ws_size,
                              hipStream_t stream) {
    const float* x  = (const float*)d_in[0];
    const float* rw = (const float*)d_in[1];
    const float* rb = (const float*)d_in[2];
    const float* w1 = (const float*)d_in[3];
    const float* b1 = (const float*)d_in[4];
    const float* w2 = (const float*)d_in[5];
    const float* b2 = (const float*)d_in[6];
    float* out = (float*)d_out;

    char* ws = (char*)d_ws;
    size_t o = 0;
    unsigned short* h   = (unsigned short*)(ws + o); o += (size_t)NSLOT * DFF * 2;
    unsigned short* w1b = (unsigned short*)(ws + o); o += (size_t)NW * 2;
    unsigned short* w2b = (unsigned short*)(ws + o); o += (size_t)NW * 2;
    unsigned short* xb  = (unsigned short*)(ws + o); o += (size_t)T_TOK * DM * 2;
    int*   tok_e      = (int*)(ws + o);   o += (size_t)NSLOT * 4;
    float* tok_g      = (float*)(ws + o); o += (size_t)NSLOT * 4;
    int*   tok_slot   = (int*)(ws + o);   o += (size_t)NSLOT * 4;
    int*   slot_token = (int*)(ws + o);   o += (size_t)NSLOT * 4;
    int*   eoff       = (int*)(ws + o);
    // y (2 split-K partials, 2*NSLOT*DM*4B = 32 MiB) aliases w1b (NW*2B):
    // gemm1 (last reader of w1b) completes before gemm2 writes y.
    float* y = (float*)w1b;

    convert_router_kernel<<<ROUTB + CONVB, 256, 0, stream>>>(
        w1, w2, w1b, w2b, x, rw, rb, tok_e, tok_g, xb);
    compact_kernel<<<1, 1024, 0, stream>>>(
        tok_e, slot_token, tok_slot, eoff);
    gemm1_kernel<<<16 * MAXTILE, 256, 0, stream>>>(
        xb, w1b, b1, slot_token, eoff, h);
    gemm2_kernel<<<8 * MAXTILE, 256, 0, stream>>>(
        h, w2b, eoff, y);
    combine_kernel<<<T_TOK / 2, 256, 0, stream>>>(
        y, b2, tok_slot, tok_g, tok_e, out);
}